// Round 2
// baseline (1667.652 us; speedup 1.0000x reference)
//
#include <hip/hip_runtime.h>
#include <cstdint>
#include <cstddef>

#define L_SEQ   1024
#define DMODEL  2048
#define DINNER  4096
#define DXB     1024
#define DSTATE  16
#define DTRANK  128
#define INTER   8192
#define ZROW    10368   // 2*DINNER + 2*DXB + DTRANK
#define SCAN_D  8

typedef __attribute__((ext_vector_type(8))) short  short8;
typedef __attribute__((ext_vector_type(4))) float  floatx4;
typedef unsigned short ushort_t;

__device__ __forceinline__ unsigned short f2bf(float f) {
  unsigned u = __float_as_uint(f);
  u += 0x7FFFu + ((u >> 16) & 1u);     // RNE
  return (unsigned short)(u >> 16);
}

__device__ __forceinline__ void gl_lds16(const void* g, void* l) {
  __builtin_amdgcn_global_load_lds(
      (const __attribute__((address_space(1))) unsigned int*)g,
      (__attribute__((address_space(3))) unsigned int*)l,
      16, 0, 0);
}

// ---------------------------------------------------------------------------
// fp32 -> bf16 convert, 8 elems/thread
// ---------------------------------------------------------------------------
__global__ void __launch_bounds__(256) cvt_kernel(
    const float* __restrict__ src, ushort_t* __restrict__ dst, int n8)
{
  int idx = blockIdx.x * 256 + threadIdx.x;
  if (idx < n8) {
    const float4* s = (const float4*)src + (size_t)idx * 2;
    float4 v0 = s[0], v1 = s[1];
    union { ushort_t u[8]; uint4 v; } o;
    o.u[0] = f2bf(v0.x); o.u[1] = f2bf(v0.y); o.u[2] = f2bf(v0.z); o.u[3] = f2bf(v0.w);
    o.u[4] = f2bf(v1.x); o.u[5] = f2bf(v1.y); o.u[6] = f2bf(v1.z); o.u[7] = f2bf(v1.w);
    ((uint4*)dst)[idx] = o.v;
  }
}

// ---------------------------------------------------------------------------
// GEMM (m97 structure): C[m,n] = sum_k A[m,k]*W[n,k], A/W bf16, fp32 accum.
// Block tile (MI*32) x (NI*32), BK=32, 256 threads = 4 waves as 2x2.
// global_load_lds width-16 staging, no padding (contiguous lane mapping).
// EPI: 0 none, 1 softplus(acc+aux[col]), 2 acc+aux[row*ldc+col]
// ---------------------------------------------------------------------------
template <int MI, int NI, int EPI>
__global__ void __launch_bounds__(256) gemm_bf16(
    const ushort_t* __restrict__ A, int lda,
    const ushort_t* __restrict__ W, int ldw,
    float* __restrict__ C, int ldc, int K,
    const float* __restrict__ aux,
    ushort_t* __restrict__ Cb, int col_lo, int ldcb)
{
  constexpr int BM = MI * 32, BN = NI * 32;
  constexpr int IA = BM / 64;          // global_load_lds issues for A
  constexpr int IB = BN / 64;
  __shared__ alignas(16) ushort_t As[BM * 32];
  __shared__ alignas(16) ushort_t Bs[BN * 32];

  const int m0 = blockIdx.y * BM;
  const int n0 = blockIdx.x * BN;
  const int t = threadIdx.x;
  const int lane = t & 63, wave = t >> 6;
  const int wm = wave & 1, wn = wave >> 1;
  const int lrow = lane & 15, quad = lane >> 4;

  // staging: lane covers row (wave*16 + lane/4), k-offset (lane%4)*8 bf16
  const int srow = wave * 16 + (lane >> 2);
  const int skof = (lane & 3) * 8;

  const ushort_t* gA[IA]; ushort_t* lA[IA];
  const ushort_t* gW[IB]; ushort_t* lB[IB];
#pragma unroll
  for (int j = 0; j < IA; ++j) {
    gA[j] = A + (size_t)(m0 + j * 64 + srow) * lda + skof;
    lA[j] = As + j * 2048 + wave * 512;     // wave-uniform; HW adds lane*16B
  }
#pragma unroll
  for (int j = 0; j < IB; ++j) {
    gW[j] = W + (size_t)(n0 + j * 64 + srow) * ldw + skof;
    lB[j] = Bs + j * 2048 + wave * 512;
  }

  floatx4 zero = {0.f, 0.f, 0.f, 0.f};
  floatx4 acc[MI][NI];
#pragma unroll
  for (int a = 0; a < MI; ++a)
#pragma unroll
    for (int b = 0; b < NI; ++b) acc[a][b] = zero;

  for (int k0 = 0; k0 < K; k0 += 32) {
#pragma unroll
    for (int j = 0; j < IA; ++j) gl_lds16(gA[j] + k0, lA[j]);
#pragma unroll
    for (int j = 0; j < IB; ++j) gl_lds16(gW[j] + k0, lB[j]);
    __syncthreads();                      // vmcnt(0) drain: LDS tiles ready

    short8 af[MI], bf_[NI];
#pragma unroll
    for (int mi = 0; mi < MI; ++mi)
      af[mi] = *(const short8*)&As[(wm * (MI * 16) + mi * 16 + lrow) * 32 + quad * 8];
#pragma unroll
    for (int ni = 0; ni < NI; ++ni)
      bf_[ni] = *(const short8*)&Bs[(wn * (NI * 16) + ni * 16 + lrow) * 32 + quad * 8];
#pragma unroll
    for (int mi = 0; mi < MI; ++mi)
#pragma unroll
      for (int ni = 0; ni < NI; ++ni)
        acc[mi][ni] = __builtin_amdgcn_mfma_f32_16x16x32_bf16(af[mi], bf_[ni], acc[mi][ni], 0, 0, 0);
    __syncthreads();                      // frags consumed before overwrite
  }

#pragma unroll
  for (int mi = 0; mi < MI; ++mi)
#pragma unroll
    for (int ni = 0; ni < NI; ++ni)
#pragma unroll
      for (int reg = 0; reg < 4; ++reg) {
        int row = m0 + wm * (MI * 16) + mi * 16 + quad * 4 + reg;
        int col = n0 + wn * (NI * 16) + ni * 16 + lrow;
        float v = acc[mi][ni][reg];
        if (EPI == 1) {
          v += aux[col];
          v = (v > 20.f) ? v : log1pf(__expf(v));
        } else if (EPI == 2) {
          v += aux[(size_t)row * ldc + col];
        }
        C[(size_t)row * ldc + col] = v;
        if (Cb != nullptr && col >= col_lo)
          Cb[(size_t)row * ldcb + (col - col_lo)] = f2bf(v);
      }
}

// ---------------------------------------------------------------------------
// RMSNorm (fp32 in, bf16 out): one block per row of D=2048
// ---------------------------------------------------------------------------
__global__ void __launch_bounds__(256) rmsnorm_kernel(
    const float* __restrict__ x, const float* __restrict__ w,
    ushort_t* __restrict__ out)
{
  const int row = blockIdx.x;
  const float* xr = x + (size_t)row * DMODEL;
  float ss = 0.f;
#pragma unroll
  for (int c = threadIdx.x * 4; c < DMODEL; c += 256 * 4) {
    float4 v = *(const float4*)(xr + c);
    ss += v.x * v.x + v.y * v.y + v.z * v.z + v.w * v.w;
  }
#pragma unroll
  for (int off = 32; off > 0; off >>= 1) ss += __shfl_down(ss, off);
  __shared__ float red[5];
  const int lane = threadIdx.x & 63, wv = threadIdx.x >> 6;
  if (lane == 0) red[wv] = ss;
  __syncthreads();
  if (threadIdx.x == 0)
    red[4] = rsqrtf((red[0] + red[1] + red[2] + red[3]) / (float)DMODEL + 1e-5f);
  __syncthreads();
  const float scale = red[4];
  ushort_t* orow = out + (size_t)row * DMODEL;
#pragma unroll
  for (int c = threadIdx.x * 4; c < DMODEL; c += 256 * 4) {
    float4 v  = *(const float4*)(xr + c);
    float4 w4 = *(const float4*)(w + c);
    ushort4 o;
    o.x = f2bf(v.x * scale * w4.x); o.y = f2bf(v.y * scale * w4.y);
    o.z = f2bf(v.z * scale * w4.z); o.w = f2bf(v.w * scale * w4.w);
    *(ushort4*)(orow + c) = o;
  }
}

// ---------------------------------------------------------------------------
// Selective scan: 16 lanes/channel, 1 state/lane, 65536 threads (256 blocks).
// Depth-8 register-ring prefetch to cover global-load latency.
// Fuses D_skip add + silu(z) gate; writes y bf16 (1024 x 4096).
// ---------------------------------------------------------------------------
__global__ void __launch_bounds__(256) scan_kernel(
    const float* __restrict__ zx,       // 1024 x ZROW
    const float* __restrict__ dt,       // 1024 x 4096
    const float* __restrict__ A_log,    // 4096 x 16
    const float* __restrict__ D_skip,   // 4096
    ushort_t* __restrict__ y)           // 1024 x 4096 bf16
{
  const int gt = blockIdx.x * 256 + threadIdx.x;   // 0..65535
  const int i  = gt >> 4;                          // channel
  const int n  = gt & 15;                          // state
  const int xcol = DINNER + ((i >> 6) << 4) + (i & 15);
  const int bcol = DINNER + DXB + ((i >> 6) << 4) + n;
  const int ccol = DINNER + 2 * DXB + (i & ~15) + n;

  const float a   = -__expf(A_log[i * DSTATE + n]);
  const float dsk = D_skip[i];
  float h = 0.f;

  const float* pdt = dt + i;
  const float* px  = zx + xcol;
  const float* pz  = zx + i;
  const float* pB  = zx + bcol;
  const float* pC  = zx + ccol;
  ushort_t*    py  = y + i;

  float dtb[SCAN_D], xb[SCAN_D], zb[SCAN_D], Bb[SCAN_D], Cb_[SCAN_D];
#pragma unroll
  for (int d = 0; d < SCAN_D; ++d) {
    dtb[d] = *pdt; pdt += DINNER;
    xb[d]  = *px;  px  += ZROW;
    zb[d]  = *pz;  pz  += ZROW;
    Bb[d]  = *pB;  pB  += ZROW;
    Cb_[d] = *pC;  pC  += ZROW;
  }

  for (int lb = 0; lb < L_SEQ; lb += SCAN_D) {
#pragma unroll
    for (int d = 0; d < SCAN_D; ++d) {
      const float dt_c = dtb[d], x_c = xb[d], z_c = zb[d];
      const float B_c = Bb[d], C_c = Cb_[d];
      if (lb + SCAN_D < L_SEQ) {          // prefetch step lb+SCAN_D+d
        dtb[d] = *pdt; pdt += DINNER;
        xb[d]  = *px;  px  += ZROW;
        zb[d]  = *pz;  pz  += ZROW;
        Bb[d]  = *pB;  pB  += ZROW;
        Cb_[d] = *pC;  pC  += ZROW;
      }
      const float e = __expf(dt_c * a);
      h = e * h + (dt_c * x_c) * B_c;
      float p = C_c * h;
      p += __shfl_xor(p, 1);
      p += __shfl_xor(p, 2);
      p += __shfl_xor(p, 4);
      p += __shfl_xor(p, 8);
      if (n == 0) {
        const float sz = z_c / (1.f + __expf(-z_c));
        *py = f2bf((p + dsk * x_c) * sz);
      }
      py += DINNER;
    }
  }
}

// ---------------------------------------------------------------------------
// hm = silu(gate) * up  (fp32 in, bf16 out)
// ---------------------------------------------------------------------------
__global__ void __launch_bounds__(256) silu_mul_kernel(
    const float* __restrict__ g, const float* __restrict__ u,
    ushort_t* __restrict__ out, int n4)
{
  const int idx = blockIdx.x * 256 + threadIdx.x;
  if (idx < n4) {
    float4 gv = ((const float4*)g)[idx];
    float4 uv = ((const float4*)u)[idx];
    ushort4 o;
    o.x = f2bf(gv.x / (1.f + __expf(-gv.x)) * uv.x);
    o.y = f2bf(gv.y / (1.f + __expf(-gv.y)) * uv.y);
    o.z = f2bf(gv.z / (1.f + __expf(-gv.z)) * uv.z);
    o.w = f2bf(gv.w / (1.f + __expf(-gv.w)) * uv.w);
    ((ushort4*)out)[idx] = o;
  }
}

// ---------------------------------------------------------------------------
extern "C" void kernel_launch(void* const* d_in, const int* in_sizes, int n_in,
                              void* d_out, int out_size, void* d_ws, size_t ws_size,
                              hipStream_t stream)
{
  const float* hidden    = (const float*)d_in[0];
  const float* rms1_w    = (const float*)d_in[1];
  const float* in_proj_w = (const float*)d_in[2];
  const float* dt_proj_w = (const float*)d_in[3];
  const float* dt_proj_b = (const float*)d_in[4];
  const float* A_log     = (const float*)d_in[5];
  const float* D_skip    = (const float*)d_in[6];
  const float* out_proj_w= (const float*)d_in[7];
  const float* rms2_w    = (const float*)d_in[8];
  const float* gate_w    = (const float*)d_in[9];
  const float* up_w      = (const float*)d_in[10];
  const float* down_w    = (const float*)d_in[11];
  float* out = (float*)d_out;

  char* ws = (char*)d_ws;
  // workspace layout (bytes)
  ushort_t* h_norm_bf = (ushort_t*)(ws + 0);           //  4,194,304
  float*    h2        = (float*)   (ws + 4194304);     //  8,388,608
  ushort_t* hn_bf     = (ushort_t*)(ws + 12582912);    //  4,194,304
  ushort_t* hm_bf     = (ushort_t*)(ws + 16777216);    // 16,777,216
  float*    zxbcdt    = (float*)   (ws + 33554432);    // 42,467,328
  ushort_t* dtA_bf    = (ushort_t*)(ws + 76021760);    //    262,144
  float*    dtbuf     = (float*)   (ws + 76283904);    // 16,777,216
  ushort_t* ybuf_bf   = (ushort_t*)(ws + 93061120);    //  8,388,608
  float*    upb       = (float*)   (ws + 101449728);   // 33,554,432
  ushort_t* wbuf      = (ushort_t*)(ws + 135004160);   // 42,467,328 (shared bf16 weight slot) -> 177,471,488 total
  float*    gateb     = zxbcdt;                        // alias (zxbcdt dead after scan)

  // 1) rmsnorm1 -> bf16
  rmsnorm_kernel<<<L_SEQ, 256, 0, stream>>>(hidden, rms1_w, h_norm_bf);
  // 2) in_proj: convert weight, GEMM -> zxbcdt fp32 (+ bf16 dt slice)
  cvt_kernel<<<(ZROW * DMODEL / 8 + 255) / 256, 256, 0, stream>>>(in_proj_w, wbuf, ZROW * DMODEL / 8);
  gemm_bf16<4, 4, 0><<<dim3(ZROW / 128, L_SEQ / 128), 256, 0, stream>>>(
      h_norm_bf, DMODEL, wbuf, DMODEL, zxbcdt, ZROW, DMODEL, nullptr,
      dtA_bf, 2 * DINNER + 2 * DXB, DTRANK);
  // 3) dt = softplus(dt_in @ dt_proj_w.T + b)
  cvt_kernel<<<(DINNER * DTRANK / 8 + 255) / 256, 256, 0, stream>>>(dt_proj_w, wbuf, DINNER * DTRANK / 8);
  gemm_bf16<4, 4, 1><<<dim3(DINNER / 128, L_SEQ / 128), 256, 0, stream>>>(
      dtA_bf, DTRANK, wbuf, DTRANK, dtbuf, DINNER, DTRANK, dt_proj_b,
      nullptr, 0, 0);
  // 4) selective scan -> ybuf bf16
  scan_kernel<<<256, 256, 0, stream>>>(zxbcdt, dtbuf, A_log, D_skip, ybuf_bf);
  // 5) h2 = hidden + y @ out_proj_w.T   (64x128 tiles -> 256 blocks)
  cvt_kernel<<<(DMODEL * DINNER / 8 + 255) / 256, 256, 0, stream>>>(out_proj_w, wbuf, DMODEL * DINNER / 8);
  gemm_bf16<2, 4, 2><<<dim3(DMODEL / 128, L_SEQ / 64), 256, 0, stream>>>(
      ybuf_bf, DINNER, wbuf, DINNER, h2, DMODEL, DINNER, hidden,
      nullptr, 0, 0);
  // 6) rmsnorm2 -> bf16
  rmsnorm_kernel<<<L_SEQ, 256, 0, stream>>>(h2, rms2_w, hn_bf);
  // 7) gate / up
  cvt_kernel<<<(INTER * DMODEL / 8 + 255) / 256, 256, 0, stream>>>(gate_w, wbuf, INTER * DMODEL / 8);
  gemm_bf16<4, 4, 0><<<dim3(INTER / 128, L_SEQ / 128), 256, 0, stream>>>(
      hn_bf, DMODEL, wbuf, DMODEL, gateb, INTER, DMODEL, nullptr, nullptr, 0, 0);
  cvt_kernel<<<(INTER * DMODEL / 8 + 255) / 256, 256, 0, stream>>>(up_w, wbuf, INTER * DMODEL / 8);
  gemm_bf16<4, 4, 0><<<dim3(INTER / 128, L_SEQ / 128), 256, 0, stream>>>(
      hn_bf, DMODEL, wbuf, DMODEL, upb, INTER, DMODEL, nullptr, nullptr, 0, 0);
  // 8) hm = silu(gate) * up -> bf16
  silu_mul_kernel<<<(L_SEQ * INTER / 4) / 256, 256, 0, stream>>>(
      gateb, upb, hm_bf, L_SEQ * INTER / 4);
  // 9) out = h2 + hm @ down_w.T   (64x128 tiles -> 256 blocks)
  cvt_kernel<<<(DMODEL * INTER / 8 + 255) / 256, 256, 0, stream>>>(down_w, wbuf, DMODEL * INTER / 8);
  gemm_bf16<2, 4, 2><<<dim3(DMODEL / 128, L_SEQ / 64), 256, 0, stream>>>(
      hm_bf, INTER, wbuf, INTER, out, DMODEL, INTER, h2,
      nullptr, 0, 0);
}

// Round 3
// 882.354 us; speedup vs baseline: 1.8900x; 1.8900x over previous
//
#include <hip/hip_runtime.h>
#include <cstdint>
#include <cstddef>

#define L_SEQ   1024
#define DMODEL  2048
#define DINNER  4096
#define DXB     1024
#define DSTATE  16
#define DTRANK  128
#define INTER   8192
#define ZROW    10368   // 2*DINNER + 2*DXB + DTRANK
#define NCHUNK  16
#define CLEN    64      // L_SEQ / NCHUNK

typedef __attribute__((ext_vector_type(8))) short  short8;
typedef __attribute__((ext_vector_type(4))) float  floatx4;
typedef unsigned short ushort_t;

__device__ __forceinline__ unsigned short f2bf(float f) {
  unsigned u = __float_as_uint(f);
  u += 0x7FFFu + ((u >> 16) & 1u);     // RNE
  return (unsigned short)(u >> 16);
}

__device__ __forceinline__ void gl_lds16(const void* g, void* l) {
  __builtin_amdgcn_global_load_lds(
      (const __attribute__((address_space(1))) unsigned int*)g,
      (__attribute__((address_space(3))) unsigned int*)l,
      16, 0, 0);
}

// ---------------------------------------------------------------------------
// fp32 -> bf16 convert, 8 elems/thread
// ---------------------------------------------------------------------------
__global__ void __launch_bounds__(256) cvt_kernel(
    const float* __restrict__ src, ushort_t* __restrict__ dst, int n8)
{
  int idx = blockIdx.x * 256 + threadIdx.x;
  if (idx < n8) {
    const float4* s = (const float4*)src + (size_t)idx * 2;
    float4 v0 = s[0], v1 = s[1];
    union { ushort_t u[8]; uint4 v; } o;
    o.u[0] = f2bf(v0.x); o.u[1] = f2bf(v0.y); o.u[2] = f2bf(v0.z); o.u[3] = f2bf(v0.w);
    o.u[4] = f2bf(v1.x); o.u[5] = f2bf(v1.y); o.u[6] = f2bf(v1.z); o.u[7] = f2bf(v1.w);
    ((uint4*)dst)[idx] = o.v;
  }
}

// ---------------------------------------------------------------------------
// GEMM (m97 structure): C[m,n] = sum_k A[m,k]*W[n,k], A/W bf16, fp32 accum.
// EPI: 0 none, 1 softplus(acc+aux[col]), 2 acc+aux[row*ldc+col]
// ---------------------------------------------------------------------------
template <int MI, int NI, int EPI>
__global__ void __launch_bounds__(256) gemm_bf16(
    const ushort_t* __restrict__ A, int lda,
    const ushort_t* __restrict__ W, int ldw,
    float* __restrict__ C, int ldc, int K,
    const float* __restrict__ aux,
    ushort_t* __restrict__ Cb, int col_lo, int ldcb)
{
  constexpr int BM = MI * 32, BN = NI * 32;
  constexpr int IA = BM / 64;
  constexpr int IB = BN / 64;
  __shared__ alignas(16) ushort_t As[BM * 32];
  __shared__ alignas(16) ushort_t Bs[BN * 32];

  const int m0 = blockIdx.y * BM;
  const int n0 = blockIdx.x * BN;
  const int t = threadIdx.x;
  const int lane = t & 63, wave = t >> 6;
  const int wm = wave & 1, wn = wave >> 1;
  const int lrow = lane & 15, quad = lane >> 4;

  const int srow = wave * 16 + (lane >> 2);
  const int skof = (lane & 3) * 8;

  const ushort_t* gA[IA]; ushort_t* lA[IA];
  const ushort_t* gW[IB]; ushort_t* lB[IB];
#pragma unroll
  for (int j = 0; j < IA; ++j) {
    gA[j] = A + (size_t)(m0 + j * 64 + srow) * lda + skof;
    lA[j] = As + j * 2048 + wave * 512;
  }
#pragma unroll
  for (int j = 0; j < IB; ++j) {
    gW[j] = W + (size_t)(n0 + j * 64 + srow) * ldw + skof;
    lB[j] = Bs + j * 2048 + wave * 512;
  }

  floatx4 zero = {0.f, 0.f, 0.f, 0.f};
  floatx4 acc[MI][NI];
#pragma unroll
  for (int a = 0; a < MI; ++a)
#pragma unroll
    for (int b = 0; b < NI; ++b) acc[a][b] = zero;

  for (int k0 = 0; k0 < K; k0 += 32) {
#pragma unroll
    for (int j = 0; j < IA; ++j) gl_lds16(gA[j] + k0, lA[j]);
#pragma unroll
    for (int j = 0; j < IB; ++j) gl_lds16(gW[j] + k0, lB[j]);
    __syncthreads();

    short8 af[MI], bf_[NI];
#pragma unroll
    for (int mi = 0; mi < MI; ++mi)
      af[mi] = *(const short8*)&As[(wm * (MI * 16) + mi * 16 + lrow) * 32 + quad * 8];
#pragma unroll
    for (int ni = 0; ni < NI; ++ni)
      bf_[ni] = *(const short8*)&Bs[(wn * (NI * 16) + ni * 16 + lrow) * 32 + quad * 8];
#pragma unroll
    for (int mi = 0; mi < MI; ++mi)
#pragma unroll
      for (int ni = 0; ni < NI; ++ni)
        acc[mi][ni] = __builtin_amdgcn_mfma_f32_16x16x32_bf16(af[mi], bf_[ni], acc[mi][ni], 0, 0, 0);
    __syncthreads();
  }

#pragma unroll
  for (int mi = 0; mi < MI; ++mi)
#pragma unroll
    for (int ni = 0; ni < NI; ++ni)
#pragma unroll
      for (int reg = 0; reg < 4; ++reg) {
        int row = m0 + wm * (MI * 16) + mi * 16 + quad * 4 + reg;
        int col = n0 + wn * (NI * 16) + ni * 16 + lrow;
        float v = acc[mi][ni][reg];
        if (EPI == 1) {
          v += aux[col];
          v = (v > 20.f) ? v : log1pf(__expf(v));
        } else if (EPI == 2) {
          v += aux[(size_t)row * ldc + col];
        }
        C[(size_t)row * ldc + col] = v;
        if (Cb != nullptr && col >= col_lo)
          Cb[(size_t)row * ldcb + (col - col_lo)] = f2bf(v);
      }
}

// ---------------------------------------------------------------------------
// RMSNorm (fp32 in, bf16 out)
// ---------------------------------------------------------------------------
__global__ void __launch_bounds__(256) rmsnorm_kernel(
    const float* __restrict__ x, const float* __restrict__ w,
    ushort_t* __restrict__ out)
{
  const int row = blockIdx.x;
  const float* xr = x + (size_t)row * DMODEL;
  float ss = 0.f;
#pragma unroll
  for (int c = threadIdx.x * 4; c < DMODEL; c += 256 * 4) {
    float4 v = *(const float4*)(xr + c);
    ss += v.x * v.x + v.y * v.y + v.z * v.z + v.w * v.w;
  }
#pragma unroll
  for (int off = 32; off > 0; off >>= 1) ss += __shfl_down(ss, off);
  __shared__ float red[5];
  const int lane = threadIdx.x & 63, wv = threadIdx.x >> 6;
  if (lane == 0) red[wv] = ss;
  __syncthreads();
  if (threadIdx.x == 0)
    red[4] = rsqrtf((red[0] + red[1] + red[2] + red[3]) / (float)DMODEL + 1e-5f);
  __syncthreads();
  const float scale = red[4];
  ushort_t* orow = out + (size_t)row * DMODEL;
#pragma unroll
  for (int c = threadIdx.x * 4; c < DMODEL; c += 256 * 4) {
    float4 v  = *(const float4*)(xr + c);
    float4 w4 = *(const float4*)(w + c);
    ushort4 o;
    o.x = f2bf(v.x * scale * w4.x); o.y = f2bf(v.y * scale * w4.y);
    o.z = f2bf(v.z * scale * w4.z); o.w = f2bf(v.w * scale * w4.w);
    *(ushort4*)(orow + c) = o;
  }
}

// ---------------------------------------------------------------------------
// Chunk-parallel selective scan (3 phases).
// Thread id in phases 1/3: gt = (chunk<<16) | (channel<<4) | state.
// ---------------------------------------------------------------------------
__global__ void __launch_bounds__(256) scan_phase1(
    const float* __restrict__ zx, const float* __restrict__ dt,
    const float* __restrict__ A_log,
    float* __restrict__ hend, float* __restrict__ aprod)
{
  const int gt = blockIdx.x * 256 + threadIdx.x;   // 0..1048575
  const int cs = gt & 65535;
  const int c  = gt >> 16;
  const int i  = cs >> 4;
  const int n  = cs & 15;
  const int l0 = c * CLEN;
  const float a = -__expf(A_log[i * DSTATE + n]);

  const float* pdt = dt + (size_t)l0 * DINNER + i;
  const float* px  = zx + (size_t)l0 * ZROW + DINNER + ((i >> 6) << 4) + (i & 15);
  const float* pB  = zx + (size_t)l0 * ZROW + DINNER + DXB + ((i >> 6) << 4) + n;

  float h = 0.f, sdt = 0.f;
#pragma unroll 4
  for (int l = 0; l < CLEN; ++l) {
    const float d = pdt[(size_t)l * DINNER];
    const float x = px[(size_t)l * ZROW];
    const float B = pB[(size_t)l * ZROW];
    sdt += d;
    h = __expf(d * a) * h + (d * x) * B;
  }
  hend[gt]  = h;
  aprod[gt] = __expf(a * sdt);
}

__global__ void __launch_bounds__(256) scan_phase2(
    const float* __restrict__ hend, const float* __restrict__ aprod,
    float* __restrict__ hstart)
{
  const int cs = blockIdx.x * 256 + threadIdx.x;   // 0..65535
  float H = 0.f;
#pragma unroll
  for (int c = 0; c < NCHUNK; ++c) {
    hstart[c * 65536 + cs] = H;
    H = aprod[c * 65536 + cs] * H + hend[c * 65536 + cs];
  }
}

__global__ void __launch_bounds__(256) scan_phase3(
    const float* __restrict__ zx, const float* __restrict__ dt,
    const float* __restrict__ A_log, const float* __restrict__ D_skip,
    const float* __restrict__ hstart,
    ushort_t* __restrict__ y)
{
  const int gt = blockIdx.x * 256 + threadIdx.x;   // 0..1048575
  const int cs = gt & 65535;
  const int c  = gt >> 16;
  const int i  = cs >> 4;
  const int n  = cs & 15;
  const int l0 = c * CLEN;
  const float a   = -__expf(A_log[i * DSTATE + n]);
  const float dsk = D_skip[i];

  const float* pdt = dt + (size_t)l0 * DINNER + i;
  const float* pz  = zx + (size_t)l0 * ZROW + i;
  const float* px  = zx + (size_t)l0 * ZROW + DINNER + ((i >> 6) << 4) + (i & 15);
  const float* pB  = zx + (size_t)l0 * ZROW + DINNER + DXB + ((i >> 6) << 4) + n;
  const float* pC  = zx + (size_t)l0 * ZROW + DINNER + 2 * DXB + (i & ~15) + n;
  ushort_t*    py  = y + (size_t)l0 * DINNER + i;

  float h = hstart[gt];
#pragma unroll 4
  for (int l = 0; l < CLEN; ++l) {
    const float d = pdt[(size_t)l * DINNER];
    const float x = px[(size_t)l * ZROW];
    const float z = pz[(size_t)l * ZROW];
    const float B = pB[(size_t)l * ZROW];
    const float C = pC[(size_t)l * ZROW];
    h = __expf(d * a) * h + (d * x) * B;
    float p = C * h;
    p += __shfl_xor(p, 1);
    p += __shfl_xor(p, 2);
    p += __shfl_xor(p, 4);
    p += __shfl_xor(p, 8);
    if (n == 0) {
      const float sz = z / (1.f + __expf(-z));
      py[(size_t)l * DINNER] = f2bf((p + dsk * x) * sz);
    }
  }
}

// ---------------------------------------------------------------------------
// hm = silu(gate) * up  (fp32 in, bf16 out)
// ---------------------------------------------------------------------------
__global__ void __launch_bounds__(256) silu_mul_kernel(
    const float* __restrict__ g, const float* __restrict__ u,
    ushort_t* __restrict__ out, int n4)
{
  const int idx = blockIdx.x * 256 + threadIdx.x;
  if (idx < n4) {
    float4 gv = ((const float4*)g)[idx];
    float4 uv = ((const float4*)u)[idx];
    ushort4 o;
    o.x = f2bf(gv.x / (1.f + __expf(-gv.x)) * uv.x);
    o.y = f2bf(gv.y / (1.f + __expf(-gv.y)) * uv.y);
    o.z = f2bf(gv.z / (1.f + __expf(-gv.z)) * uv.z);
    o.w = f2bf(gv.w / (1.f + __expf(-gv.w)) * uv.w);
    ((ushort4*)out)[idx] = o;
  }
}

// ---------------------------------------------------------------------------
extern "C" void kernel_launch(void* const* d_in, const int* in_sizes, int n_in,
                              void* d_out, int out_size, void* d_ws, size_t ws_size,
                              hipStream_t stream)
{
  const float* hidden    = (const float*)d_in[0];
  const float* rms1_w    = (const float*)d_in[1];
  const float* in_proj_w = (const float*)d_in[2];
  const float* dt_proj_w = (const float*)d_in[3];
  const float* dt_proj_b = (const float*)d_in[4];
  const float* A_log     = (const float*)d_in[5];
  const float* D_skip    = (const float*)d_in[6];
  const float* out_proj_w= (const float*)d_in[7];
  const float* rms2_w    = (const float*)d_in[8];
  const float* gate_w    = (const float*)d_in[9];
  const float* up_w      = (const float*)d_in[10];
  const float* down_w    = (const float*)d_in[11];
  float* out = (float*)d_out;

  char* ws = (char*)d_ws;
  ushort_t* h_norm_bf = (ushort_t*)(ws + 0);           //  4,194,304
  float*    h2        = (float*)   (ws + 4194304);     //  8,388,608
  ushort_t* hn_bf     = (ushort_t*)(ws + 12582912);    //  4,194,304
  ushort_t* hm_bf     = (ushort_t*)(ws + 16777216);    // 16,777,216
  float*    zxbcdt    = (float*)   (ws + 33554432);    // 42,467,328
  ushort_t* dtA_bf    = (ushort_t*)(ws + 76021760);    //    262,144
  float*    dtbuf     = (float*)   (ws + 76283904);    // 16,777,216
  ushort_t* ybuf_bf   = (ushort_t*)(ws + 93061120);    //  8,388,608
  float*    upb       = (float*)   (ws + 101449728);   // 33,554,432
  ushort_t* wbuf      = (ushort_t*)(ws + 135004160);   // 42,467,328 -> 177,471,488 total
  float*    gateb     = zxbcdt;                        // alias (dead after scan)
  // scan scratch aliases upb (dead until step 7)
  float*    hend_s    = (float*)(ws + 101449728);      // 4,194,304
  float*    aprod_s   = (float*)(ws + 105644032);      // 4,194,304
  float*    hstart_s  = (float*)(ws + 109838336);      // 4,194,304

  // 1) rmsnorm1 -> bf16
  rmsnorm_kernel<<<L_SEQ, 256, 0, stream>>>(hidden, rms1_w, h_norm_bf);
  // 2) in_proj -> zxbcdt fp32 (+ bf16 dt slice)
  cvt_kernel<<<(ZROW * DMODEL / 8 + 255) / 256, 256, 0, stream>>>(in_proj_w, wbuf, ZROW * DMODEL / 8);
  gemm_bf16<4, 4, 0><<<dim3(ZROW / 128, L_SEQ / 128), 256, 0, stream>>>(
      h_norm_bf, DMODEL, wbuf, DMODEL, zxbcdt, ZROW, DMODEL, nullptr,
      dtA_bf, 2 * DINNER + 2 * DXB, DTRANK);
  // 3) dt = softplus(dt_in @ dt_proj_w.T + b)
  cvt_kernel<<<(DINNER * DTRANK / 8 + 255) / 256, 256, 0, stream>>>(dt_proj_w, wbuf, DINNER * DTRANK / 8);
  gemm_bf16<4, 4, 1><<<dim3(DINNER / 128, L_SEQ / 128), 256, 0, stream>>>(
      dtA_bf, DTRANK, wbuf, DTRANK, dtbuf, DINNER, DTRANK, dt_proj_b,
      nullptr, 0, 0);
  // 4) chunk-parallel scan -> ybuf bf16
  scan_phase1<<<4096, 256, 0, stream>>>(zxbcdt, dtbuf, A_log, hend_s, aprod_s);
  scan_phase2<<<256, 256, 0, stream>>>(hend_s, aprod_s, hstart_s);
  scan_phase3<<<4096, 256, 0, stream>>>(zxbcdt, dtbuf, A_log, D_skip, hstart_s, ybuf_bf);
  // 5) h2 = hidden + y @ out_proj_w.T
  cvt_kernel<<<(DMODEL * DINNER / 8 + 255) / 256, 256, 0, stream>>>(out_proj_w, wbuf, DMODEL * DINNER / 8);
  gemm_bf16<2, 4, 2><<<dim3(DMODEL / 128, L_SEQ / 64), 256, 0, stream>>>(
      ybuf_bf, DINNER, wbuf, DINNER, h2, DMODEL, DINNER, hidden,
      nullptr, 0, 0);
  // 6) rmsnorm2 -> bf16
  rmsnorm_kernel<<<L_SEQ, 256, 0, stream>>>(h2, rms2_w, hn_bf);
  // 7) gate / up
  cvt_kernel<<<(INTER * DMODEL / 8 + 255) / 256, 256, 0, stream>>>(gate_w, wbuf, INTER * DMODEL / 8);
  gemm_bf16<4, 4, 0><<<dim3(INTER / 128, L_SEQ / 128), 256, 0, stream>>>(
      hn_bf, DMODEL, wbuf, DMODEL, gateb, INTER, DMODEL, nullptr, nullptr, 0, 0);
  cvt_kernel<<<(INTER * DMODEL / 8 + 255) / 256, 256, 0, stream>>>(up_w, wbuf, INTER * DMODEL / 8);
  gemm_bf16<4, 4, 0><<<dim3(INTER / 128, L_SEQ / 128), 256, 0, stream>>>(
      hn_bf, DMODEL, wbuf, DMODEL, upb, INTER, DMODEL, nullptr, nullptr, 0, 0);
  // 8) hm = silu(gate) * up -> bf16
  silu_mul_kernel<<<(L_SEQ * INTER / 4) / 256, 256, 0, stream>>>(
      gateb, upb, hm_bf, L_SEQ * INTER / 4);
  // 9) out = h2 + hm @ down_w.T
  cvt_kernel<<<(DMODEL * INTER / 8 + 255) / 256, 256, 0, stream>>>(down_w, wbuf, DMODEL * INTER / 8);
  gemm_bf16<2, 4, 2><<<dim3(DMODEL / 128, L_SEQ / 64), 256, 0, stream>>>(
      hm_bf, INTER, wbuf, INTER, out, DMODEL, INTER, h2,
      nullptr, 0, 0);
}

// Round 4
// 760.532 us; speedup vs baseline: 2.1927x; 1.1602x over previous
//
#include <hip/hip_runtime.h>
#include <cstdint>
#include <cstddef>

#define L_SEQ   1024
#define DMODEL  2048
#define DINNER  4096
#define DXB     1024
#define DSTATE  16
#define DTRANK  128
#define INTER   8192
#define ZROW    10368   // 2*DINNER + 2*DXB + DTRANK
#define NCHUNK  16
#define CLEN    64      // L_SEQ / NCHUNK

typedef __attribute__((ext_vector_type(8))) short  short8;
typedef __attribute__((ext_vector_type(4))) float  floatx4;
typedef unsigned short ushort_t;

__device__ __forceinline__ unsigned short f2bf(float f) {
  unsigned u = __float_as_uint(f);
  u += 0x7FFFu + ((u >> 16) & 1u);     // RNE
  return (unsigned short)(u >> 16);
}
__device__ __forceinline__ float bf2f(unsigned short h) {
  return __uint_as_float(((unsigned)h) << 16);
}

__device__ __forceinline__ void gl_lds16(const void* g, void* l) {
  __builtin_amdgcn_global_load_lds(
      (const __attribute__((address_space(1))) unsigned int*)g,
      (__attribute__((address_space(3))) unsigned int*)l,
      16, 0, 0);
}

// ---------------------------------------------------------------------------
// fp32 -> bf16 convert, 8 elems/thread
// ---------------------------------------------------------------------------
__global__ void __launch_bounds__(256) cvt_kernel(
    const float* __restrict__ src, ushort_t* __restrict__ dst, int n8)
{
  int idx = blockIdx.x * 256 + threadIdx.x;
  if (idx < n8) {
    const float4* s = (const float4*)src + (size_t)idx * 2;
    float4 v0 = s[0], v1 = s[1];
    union { ushort_t u[8]; uint4 v; } o;
    o.u[0] = f2bf(v0.x); o.u[1] = f2bf(v0.y); o.u[2] = f2bf(v0.z); o.u[3] = f2bf(v0.w);
    o.u[4] = f2bf(v1.x); o.u[5] = f2bf(v1.y); o.u[6] = f2bf(v1.z); o.u[7] = f2bf(v1.w);
    ((uint4*)dst)[idx] = o.v;
  }
}

// ---------------------------------------------------------------------------
// GEMM: C[m,n] = sum_k A[m,k]*W[n,k], bf16 in, fp32 accum.
// Double-buffered LDS (one barrier/iter, prefetch overlaps MFMA phase).
// Split-K via blockIdx.z: chunk kz covers columns [kz*K, (kz+1)*K),
// partial written to C + kz*M*ldc.
// EPI: 0 none, 1 softplus(acc+aux[col]), 2 acc+aux[row*ldc+col]
// WF32: write fp32 C.  Cb!=null: also/only write bf16 (cols >= col_lo).
// ---------------------------------------------------------------------------
template <int MI, int NI, int EPI, bool WF32>
__global__ void __launch_bounds__(256) gemm_bf16(
    const ushort_t* __restrict__ A, int lda,
    const ushort_t* __restrict__ W, int ldw,
    float* __restrict__ C, int ldc, int K,
    const float* __restrict__ aux,
    ushort_t* __restrict__ Cb, int col_lo, int ldcb)
{
  constexpr int BM = MI * 32, BN = NI * 32;
  constexpr int IA = BM / 64, IB = BN / 64;
  constexpr int ASZ = BM * 32, BSZ = BN * 32;
  __shared__ alignas(16) ushort_t As[2 * ASZ];
  __shared__ alignas(16) ushort_t Bs[2 * BSZ];

  const int kz = blockIdx.z;
  A += (size_t)kz * K;
  W += (size_t)kz * K;
  C += (size_t)kz * gridDim.y * BM * ldc;

  const int m0 = blockIdx.y * BM;
  const int n0 = blockIdx.x * BN;
  const int t = threadIdx.x;
  const int lane = t & 63, wave = t >> 6;
  const int wm = wave & 1, wn = wave >> 1;
  const int lrow = lane & 15, quad = lane >> 4;

  const int srow = wave * 16 + (lane >> 2);
  const int skof = (lane & 3) * 8;

  const ushort_t* gA[IA]; ushort_t* lA[IA];
  const ushort_t* gW[IB]; ushort_t* lB[IB];
#pragma unroll
  for (int j = 0; j < IA; ++j) {
    gA[j] = A + (size_t)(m0 + j * 64 + srow) * lda + skof;
    lA[j] = As + j * 2048 + wave * 512;
  }
#pragma unroll
  for (int j = 0; j < IB; ++j) {
    gW[j] = W + (size_t)(n0 + j * 64 + srow) * ldw + skof;
    lB[j] = Bs + j * 2048 + wave * 512;
  }

  floatx4 zero = {0.f, 0.f, 0.f, 0.f};
  floatx4 acc[MI][NI];
#pragma unroll
  for (int a = 0; a < MI; ++a)
#pragma unroll
    for (int b = 0; b < NI; ++b) acc[a][b] = zero;

  // prologue: stage k0=0 into buffer 0
#pragma unroll
  for (int j = 0; j < IA; ++j) gl_lds16(gA[j], lA[j]);
#pragma unroll
  for (int j = 0; j < IB; ++j) gl_lds16(gW[j], lB[j]);

  int buf = 0;
  for (int k0 = 0; k0 < K; k0 += 32) {
    __syncthreads();                 // drains vmcnt: buf[buf] is ready
    const int nk = k0 + 32;
    if (nk < K) {                    // prefetch next tile into other buffer
      const int nb = buf ^ 1;
#pragma unroll
      for (int j = 0; j < IA; ++j) gl_lds16(gA[j] + nk, lA[j] + nb * ASZ);
#pragma unroll
      for (int j = 0; j < IB; ++j) gl_lds16(gW[j] + nk, lB[j] + nb * BSZ);
    }

    short8 af[MI], bf_[NI];
#pragma unroll
    for (int mi = 0; mi < MI; ++mi)
      af[mi] = *(const short8*)&As[buf * ASZ + (wm * (MI * 16) + mi * 16 + lrow) * 32 + quad * 8];
#pragma unroll
    for (int ni = 0; ni < NI; ++ni)
      bf_[ni] = *(const short8*)&Bs[buf * BSZ + (wn * (NI * 16) + ni * 16 + lrow) * 32 + quad * 8];
#pragma unroll
    for (int mi = 0; mi < MI; ++mi)
#pragma unroll
      for (int ni = 0; ni < NI; ++ni)
        acc[mi][ni] = __builtin_amdgcn_mfma_f32_16x16x32_bf16(af[mi], bf_[ni], acc[mi][ni], 0, 0, 0);
    buf ^= 1;
  }

#pragma unroll
  for (int mi = 0; mi < MI; ++mi)
#pragma unroll
    for (int ni = 0; ni < NI; ++ni)
#pragma unroll
      for (int reg = 0; reg < 4; ++reg) {
        int row = m0 + wm * (MI * 16) + mi * 16 + quad * 4 + reg;
        int col = n0 + wn * (NI * 16) + ni * 16 + lrow;
        float v = acc[mi][ni][reg];
        if (EPI == 1) {
          v += aux[col];
          v = (v > 20.f) ? v : log1pf(__expf(v));
        } else if (EPI == 2) {
          v += aux[(size_t)row * ldc + col];
        }
        if constexpr (WF32)
          C[(size_t)row * ldc + col] = v;
        if (Cb != nullptr && col >= col_lo)
          Cb[(size_t)row * ldcb + (col - col_lo)] = f2bf(v);
      }
}

// ---------------------------------------------------------------------------
// split-K reduce: out = aux + sum_{s<S} part[s]   (fp32, float4)
// ---------------------------------------------------------------------------
template <int S>
__global__ void __launch_bounds__(256) reduce_add_kernel(
    const float* __restrict__ part, int stride4,
    const float* __restrict__ aux, float* __restrict__ out, int n4)
{
  int idx = blockIdx.x * 256 + threadIdx.x;
  if (idx < n4) {
    float4 v = ((const float4*)aux)[idx];
#pragma unroll
    for (int s = 0; s < S; ++s) {
      float4 p = ((const float4*)part)[(size_t)s * stride4 + idx];
      v.x += p.x; v.y += p.y; v.z += p.z; v.w += p.w;
    }
    ((float4*)out)[idx] = v;
  }
}

// ---------------------------------------------------------------------------
// RMSNorm (fp32 in, bf16 out)
// ---------------------------------------------------------------------------
__global__ void __launch_bounds__(256) rmsnorm_kernel(
    const float* __restrict__ x, const float* __restrict__ w,
    ushort_t* __restrict__ out)
{
  const int row = blockIdx.x;
  const float* xr = x + (size_t)row * DMODEL;
  float ss = 0.f;
#pragma unroll
  for (int c = threadIdx.x * 4; c < DMODEL; c += 256 * 4) {
    float4 v = *(const float4*)(xr + c);
    ss += v.x * v.x + v.y * v.y + v.z * v.z + v.w * v.w;
  }
#pragma unroll
  for (int off = 32; off > 0; off >>= 1) ss += __shfl_down(ss, off);
  __shared__ float red[5];
  const int lane = threadIdx.x & 63, wv = threadIdx.x >> 6;
  if (lane == 0) red[wv] = ss;
  __syncthreads();
  if (threadIdx.x == 0)
    red[4] = rsqrtf((red[0] + red[1] + red[2] + red[3]) / (float)DMODEL + 1e-5f);
  __syncthreads();
  const float scale = red[4];
  ushort_t* orow = out + (size_t)row * DMODEL;
#pragma unroll
  for (int c = threadIdx.x * 4; c < DMODEL; c += 256 * 4) {
    float4 v  = *(const float4*)(xr + c);
    float4 w4 = *(const float4*)(w + c);
    ushort4 o;
    o.x = f2bf(v.x * scale * w4.x); o.y = f2bf(v.y * scale * w4.y);
    o.z = f2bf(v.z * scale * w4.z); o.w = f2bf(v.w * scale * w4.w);
    *(ushort4*)(orow + c) = o;
  }
}

// ---------------------------------------------------------------------------
// Chunk-parallel selective scan (3 phases).
// ---------------------------------------------------------------------------
__global__ void __launch_bounds__(256) scan_phase1(
    const float* __restrict__ zx, const float* __restrict__ dt,
    const float* __restrict__ A_log,
    float* __restrict__ hend, float* __restrict__ aprod)
{
  const int gt = blockIdx.x * 256 + threadIdx.x;   // 0..1048575
  const int cs = gt & 65535;
  const int c  = gt >> 16;
  const int i  = cs >> 4;
  const int n  = cs & 15;
  const int l0 = c * CLEN;
  const float a = -__expf(A_log[i * DSTATE + n]);

  const float* pdt = dt + (size_t)l0 * DINNER + i;
  const float* px  = zx + (size_t)l0 * ZROW + DINNER + ((i >> 6) << 4) + (i & 15);
  const float* pB  = zx + (size_t)l0 * ZROW + DINNER + DXB + ((i >> 6) << 4) + n;

  float h = 0.f, sdt = 0.f;
#pragma unroll 4
  for (int l = 0; l < CLEN; ++l) {
    const float d = pdt[(size_t)l * DINNER];
    const float x = px[(size_t)l * ZROW];
    const float B = pB[(size_t)l * ZROW];
    sdt += d;
    h = __expf(d * a) * h + (d * x) * B;
  }
  hend[gt]  = h;
  aprod[gt] = __expf(a * sdt);
}

__global__ void __launch_bounds__(256) scan_phase2(
    const float* __restrict__ hend, const float* __restrict__ aprod,
    float* __restrict__ hstart)
{
  const int cs = blockIdx.x * 256 + threadIdx.x;   // 0..65535
  float H = 0.f;
#pragma unroll
  for (int c = 0; c < NCHUNK; ++c) {
    hstart[c * 65536 + cs] = H;
    H = aprod[c * 65536 + cs] * H + hend[c * 65536 + cs];
  }
}

__global__ void __launch_bounds__(256) scan_phase3(
    const float* __restrict__ zx, const float* __restrict__ dt,
    const float* __restrict__ A_log, const float* __restrict__ D_skip,
    const float* __restrict__ hstart,
    ushort_t* __restrict__ y)
{
  const int gt = blockIdx.x * 256 + threadIdx.x;   // 0..1048575
  const int cs = gt & 65535;
  const int c  = gt >> 16;
  const int i  = cs >> 4;
  const int n  = cs & 15;
  const int l0 = c * CLEN;
  const float a   = -__expf(A_log[i * DSTATE + n]);
  const float dsk = D_skip[i];

  const float* pdt = dt + (size_t)l0 * DINNER + i;
  const float* pz  = zx + (size_t)l0 * ZROW + i;
  const float* px  = zx + (size_t)l0 * ZROW + DINNER + ((i >> 6) << 4) + (i & 15);
  const float* pB  = zx + (size_t)l0 * ZROW + DINNER + DXB + ((i >> 6) << 4) + n;
  const float* pC  = zx + (size_t)l0 * ZROW + DINNER + 2 * DXB + (i & ~15) + n;
  ushort_t*    py  = y + (size_t)l0 * DINNER + i;

  float h = hstart[gt];
#pragma unroll 4
  for (int l = 0; l < CLEN; ++l) {
    const float d = pdt[(size_t)l * DINNER];
    const float x = px[(size_t)l * ZROW];
    const float z = pz[(size_t)l * ZROW];
    const float B = pB[(size_t)l * ZROW];
    const float C = pC[(size_t)l * ZROW];
    h = __expf(d * a) * h + (d * x) * B;
    float p = C * h;
    p += __shfl_xor(p, 1);
    p += __shfl_xor(p, 2);
    p += __shfl_xor(p, 4);
    p += __shfl_xor(p, 8);
    if (n == 0) {
      const float sz = z / (1.f + __expf(-z));
      py[(size_t)l * DINNER] = f2bf((p + dsk * x) * sz);
    }
  }
}

// ---------------------------------------------------------------------------
// hm = silu(gate) * up  (bf16 in, bf16 out), 8 elems/thread
// ---------------------------------------------------------------------------
__global__ void __launch_bounds__(256) silu_mul_kernel(
    const ushort_t* __restrict__ g, const ushort_t* __restrict__ u,
    ushort_t* __restrict__ out, int n8)
{
  const int idx = blockIdx.x * 256 + threadIdx.x;
  if (idx < n8) {
    union { uint4 v; ushort_t u[8]; } gv, uv, ov;
    gv.v = ((const uint4*)g)[idx];
    uv.v = ((const uint4*)u)[idx];
#pragma unroll
    for (int j = 0; j < 8; ++j) {
      float gf = bf2f(gv.u[j]), uf = bf2f(uv.u[j]);
      ov.u[j] = f2bf(gf / (1.f + __expf(-gf)) * uf);
    }
    ((uint4*)out)[idx] = ov.v;
  }
}

// ---------------------------------------------------------------------------
extern "C" void kernel_launch(void* const* d_in, const int* in_sizes, int n_in,
                              void* d_out, int out_size, void* d_ws, size_t ws_size,
                              hipStream_t stream)
{
  const float* hidden    = (const float*)d_in[0];
  const float* rms1_w    = (const float*)d_in[1];
  const float* in_proj_w = (const float*)d_in[2];
  const float* dt_proj_w = (const float*)d_in[3];
  const float* dt_proj_b = (const float*)d_in[4];
  const float* A_log     = (const float*)d_in[5];
  const float* D_skip    = (const float*)d_in[6];
  const float* out_proj_w= (const float*)d_in[7];
  const float* rms2_w    = (const float*)d_in[8];
  const float* gate_w    = (const float*)d_in[9];
  const float* up_w      = (const float*)d_in[10];
  const float* down_w    = (const float*)d_in[11];
  float* out = (float*)d_out;

  char* ws = (char*)d_ws;
  // ---- arena (151,781,376 bytes total; proven ws >= 177 MB) ----
  ushort_t* h_norm_bf = (ushort_t*)(ws + 0);            // 4,194,304
  float*    h2        = (float*)   (ws + 4194304);      // 8,388,608
  ushort_t* hn_bf     = (ushort_t*)(ws + 12582912);     // 4,194,304
  // SLAB1 @ 16,777,216 (48 MB): zxbcdt -> part1 -> up_bf/hm_bf
  float*    zxbcdt    = (float*)   (ws + 16777216);     // 42,467,328
  float*    part1     = (float*)   (ws + 16777216);     // 33,554,432 (after scan)
  ushort_t* up_bf     = (ushort_t*)(ws + 16777216);     // 16,777,216 (after reduce1)
  ushort_t* hm_bf     = (ushort_t*)(ws + 33554432);     // 16,777,216
  // SLAB2 @ 67,108,864 (33.5 MB): dtbuf+scan scratch -> gate_bf -> part2
  float*    dtbuf     = (float*)   (ws + 67108864);     // 16,777,216
  float*    hend_s    = (float*)   (ws + 83886080);     //  4,194,304
  float*    aprod_s   = (float*)   (ws + 88080384);     //  4,194,304
  float*    hstart_s  = (float*)   (ws + 92274688);     //  4,194,304
  ushort_t* gate_bf   = (ushort_t*)(ws + 67108864);     // 16,777,216 (after scan)
  float*    part2     = (float*)   (ws + 67108864);     // 33,554,432 (after silu)
  ushort_t* ybuf_bf   = (ushort_t*)(ws + 100663296);    //  8,388,608
  ushort_t* dtA_bf    = (ushort_t*)(ws + 109051904);    //    262,144
  ushort_t* wbuf      = (ushort_t*)(ws + 109314048);    // 42,467,328 -> ends 151,781,376

  // 1) rmsnorm1 -> bf16
  rmsnorm_kernel<<<L_SEQ, 256, 0, stream>>>(hidden, rms1_w, h_norm_bf);
  // 2) in_proj -> zxbcdt fp32 (+ bf16 dt slice)
  cvt_kernel<<<(ZROW * DMODEL / 8 + 255) / 256, 256, 0, stream>>>(in_proj_w, wbuf, ZROW * DMODEL / 8);
  gemm_bf16<4, 4, 0, true><<<dim3(ZROW / 128, L_SEQ / 128, 1), 256, 0, stream>>>(
      h_norm_bf, DMODEL, wbuf, DMODEL, zxbcdt, ZROW, DMODEL, nullptr,
      dtA_bf, 2 * DINNER + 2 * DXB, DTRANK);
  // 3) dt = softplus(dt_in @ dt_proj_w.T + b)
  cvt_kernel<<<(DINNER * DTRANK / 8 + 255) / 256, 256, 0, stream>>>(dt_proj_w, wbuf, DINNER * DTRANK / 8);
  gemm_bf16<4, 4, 1, true><<<dim3(DINNER / 128, L_SEQ / 128, 1), 256, 0, stream>>>(
      dtA_bf, DTRANK, wbuf, DTRANK, dtbuf, DINNER, DTRANK, dt_proj_b,
      nullptr, 0, 0);
  // 4) chunk-parallel scan -> ybuf bf16
  scan_phase1<<<4096, 256, 0, stream>>>(zxbcdt, dtbuf, A_log, hend_s, aprod_s);
  scan_phase2<<<256, 256, 0, stream>>>(hend_s, aprod_s, hstart_s);
  scan_phase3<<<4096, 256, 0, stream>>>(zxbcdt, dtbuf, A_log, D_skip, hstart_s, ybuf_bf);
  // 5) out_proj split-K x4 -> part1; reduce (+hidden) -> h2
  cvt_kernel<<<(DMODEL * DINNER / 8 + 255) / 256, 256, 0, stream>>>(out_proj_w, wbuf, DMODEL * DINNER / 8);
  gemm_bf16<2, 4, 0, true><<<dim3(DMODEL / 128, L_SEQ / 64, 4), 256, 0, stream>>>(
      ybuf_bf, DINNER, wbuf, DINNER, part1, DMODEL, DINNER / 4, nullptr,
      nullptr, 0, 0);
  reduce_add_kernel<4><<<(L_SEQ * DMODEL / 4) / 256, 256, 0, stream>>>(
      part1, L_SEQ * DMODEL / 4, hidden, h2, L_SEQ * DMODEL / 4);
  // 6) rmsnorm2 -> bf16
  rmsnorm_kernel<<<L_SEQ, 256, 0, stream>>>(h2, rms2_w, hn_bf);
  // 7) gate / up (bf16-only outputs)
  cvt_kernel<<<(INTER * DMODEL / 8 + 255) / 256, 256, 0, stream>>>(gate_w, wbuf, INTER * DMODEL / 8);
  gemm_bf16<4, 4, 0, false><<<dim3(INTER / 128, L_SEQ / 128, 1), 256, 0, stream>>>(
      hn_bf, DMODEL, wbuf, DMODEL, nullptr, INTER, DMODEL, nullptr,
      gate_bf, 0, INTER);
  cvt_kernel<<<(INTER * DMODEL / 8 + 255) / 256, 256, 0, stream>>>(up_w, wbuf, INTER * DMODEL / 8);
  gemm_bf16<4, 4, 0, false><<<dim3(INTER / 128, L_SEQ / 128, 1), 256, 0, stream>>>(
      hn_bf, DMODEL, wbuf, DMODEL, nullptr, INTER, DMODEL, nullptr,
      up_bf, 0, INTER);
  // 8) hm = silu(gate) * up -> bf16
  silu_mul_kernel<<<(L_SEQ * INTER / 8) / 256, 256, 0, stream>>>(
      gate_bf, up_bf, hm_bf, L_SEQ * INTER / 8);
  // 9) down split-K x4 -> part2; reduce (+h2) -> out
  cvt_kernel<<<(DMODEL * INTER / 8 + 255) / 256, 256, 0, stream>>>(down_w, wbuf, DMODEL * INTER / 8);
  gemm_bf16<2, 4, 0, true><<<dim3(DMODEL / 128, L_SEQ / 64, 4), 256, 0, stream>>>(
      hm_bf, INTER, wbuf, INTER, part2, DMODEL, INTER / 4, nullptr,
      nullptr, 0, 0);
  reduce_add_kernel<4><<<(L_SEQ * DMODEL / 4) / 256, 256, 0, stream>>>(
      part2, L_SEQ * DMODEL / 4, h2, out, L_SEQ * DMODEL / 4);
}

// Round 5
// 680.534 us; speedup vs baseline: 2.4505x; 1.1176x over previous
//
#include <hip/hip_runtime.h>
#include <cstdint>
#include <cstddef>

#define L_SEQ   1024
#define DMODEL  2048
#define DINNER  4096
#define DXB     1024
#define DSTATE  16
#define DTRANK  128
#define INTER   8192
#define ZROW    10368   // 2*DINNER + 2*DXB + DTRANK
#define NCHUNK  64
#define CLEN    16      // L_SEQ / NCHUNK

typedef __attribute__((ext_vector_type(8))) short  short8;
typedef __attribute__((ext_vector_type(4))) float  floatx4;
typedef unsigned short ushort_t;

__device__ __forceinline__ unsigned short f2bf(float f) {
  unsigned u = __float_as_uint(f);
  u += 0x7FFFu + ((u >> 16) & 1u);     // RNE
  return (unsigned short)(u >> 16);
}
__device__ __forceinline__ float bf2f(unsigned short h) {
  return __uint_as_float(((unsigned)h) << 16);
}

__device__ __forceinline__ void gl_lds16(const void* g, void* l) {
  __builtin_amdgcn_global_load_lds(
      (const __attribute__((address_space(1))) unsigned int*)g,
      (__attribute__((address_space(3))) unsigned int*)l,
      16, 0, 0);
}

// ---------------------------------------------------------------------------
// fp32 -> bf16 convert, 8 elems/thread
// ---------------------------------------------------------------------------
__global__ void __launch_bounds__(256) cvt_kernel(
    const float* __restrict__ src, ushort_t* __restrict__ dst, int n8)
{
  int idx = blockIdx.x * 256 + threadIdx.x;
  if (idx < n8) {
    const float4* s = (const float4*)src + (size_t)idx * 2;
    float4 v0 = s[0], v1 = s[1];
    union { ushort_t u[8]; uint4 v; } o;
    o.u[0] = f2bf(v0.x); o.u[1] = f2bf(v0.y); o.u[2] = f2bf(v0.z); o.u[3] = f2bf(v0.w);
    o.u[4] = f2bf(v1.x); o.u[5] = f2bf(v1.y); o.u[6] = f2bf(v1.z); o.u[7] = f2bf(v1.w);
    ((uint4*)dst)[idx] = o.v;
  }
}

// ---------------------------------------------------------------------------
// GEMM: C[m,n] = sum_k A[m,k]*W[n,k], bf16 in, fp32 accum.
// Double-buffered LDS (one barrier/iter). Split-K via blockIdx.z.
// EPI: 0 none, 1 softplus(acc+aux[col]). WF32: write fp32 C.
// Cb!=null: also/only write bf16 (cols >= col_lo).
// ---------------------------------------------------------------------------
template <int MI, int NI, int EPI, bool WF32>
__global__ void __launch_bounds__(256) gemm_bf16(
    const ushort_t* __restrict__ A, int lda,
    const ushort_t* __restrict__ W, int ldw,
    float* __restrict__ C, int ldc, int K,
    const float* __restrict__ aux,
    ushort_t* __restrict__ Cb, int col_lo, int ldcb)
{
  constexpr int BM = MI * 32, BN = NI * 32;
  constexpr int IA = BM / 64, IB = BN / 64;
  constexpr int ASZ = BM * 32, BSZ = BN * 32;
  __shared__ alignas(16) ushort_t As[2 * ASZ];
  __shared__ alignas(16) ushort_t Bs[2 * BSZ];

  const int kz = blockIdx.z;
  A += (size_t)kz * K;
  W += (size_t)kz * K;
  C += (size_t)kz * gridDim.y * BM * ldc;

  const int m0 = blockIdx.y * BM;
  const int n0 = blockIdx.x * BN;
  const int t = threadIdx.x;
  const int lane = t & 63, wave = t >> 6;
  const int wm = wave & 1, wn = wave >> 1;
  const int lrow = lane & 15, quad = lane >> 4;

  const int srow = wave * 16 + (lane >> 2);
  const int skof = (lane & 3) * 8;

  const ushort_t* gA[IA]; ushort_t* lA[IA];
  const ushort_t* gW[IB]; ushort_t* lB[IB];
#pragma unroll
  for (int j = 0; j < IA; ++j) {
    gA[j] = A + (size_t)(m0 + j * 64 + srow) * lda + skof;
    lA[j] = As + j * 2048 + wave * 512;
  }
#pragma unroll
  for (int j = 0; j < IB; ++j) {
    gW[j] = W + (size_t)(n0 + j * 64 + srow) * ldw + skof;
    lB[j] = Bs + j * 2048 + wave * 512;
  }

  floatx4 zero = {0.f, 0.f, 0.f, 0.f};
  floatx4 acc[MI][NI];
#pragma unroll
  for (int a = 0; a < MI; ++a)
#pragma unroll
    for (int b = 0; b < NI; ++b) acc[a][b] = zero;

#pragma unroll
  for (int j = 0; j < IA; ++j) gl_lds16(gA[j], lA[j]);
#pragma unroll
  for (int j = 0; j < IB; ++j) gl_lds16(gW[j], lB[j]);

  int buf = 0;
  for (int k0 = 0; k0 < K; k0 += 32) {
    __syncthreads();                 // drains vmcnt: buf[buf] is ready
    const int nk = k0 + 32;
    if (nk < K) {
      const int nb = buf ^ 1;
#pragma unroll
      for (int j = 0; j < IA; ++j) gl_lds16(gA[j] + nk, lA[j] + nb * ASZ);
#pragma unroll
      for (int j = 0; j < IB; ++j) gl_lds16(gW[j] + nk, lB[j] + nb * BSZ);
    }

    short8 af[MI], bf_[NI];
#pragma unroll
    for (int mi = 0; mi < MI; ++mi)
      af[mi] = *(const short8*)&As[buf * ASZ + (wm * (MI * 16) + mi * 16 + lrow) * 32 + quad * 8];
#pragma unroll
    for (int ni = 0; ni < NI; ++ni)
      bf_[ni] = *(const short8*)&Bs[buf * BSZ + (wn * (NI * 16) + ni * 16 + lrow) * 32 + quad * 8];
#pragma unroll
    for (int mi = 0; mi < MI; ++mi)
#pragma unroll
      for (int ni = 0; ni < NI; ++ni)
        acc[mi][ni] = __builtin_amdgcn_mfma_f32_16x16x32_bf16(af[mi], bf_[ni], acc[mi][ni], 0, 0, 0);
    buf ^= 1;
  }

#pragma unroll
  for (int mi = 0; mi < MI; ++mi)
#pragma unroll
    for (int ni = 0; ni < NI; ++ni)
#pragma unroll
      for (int reg = 0; reg < 4; ++reg) {
        int row = m0 + wm * (MI * 16) + mi * 16 + quad * 4 + reg;
        int col = n0 + wn * (NI * 16) + ni * 16 + lrow;
        float v = acc[mi][ni][reg];
        if (EPI == 1) {
          v += aux[col];
          v = (v > 20.f) ? v : log1pf(__expf(v));
        }
        if constexpr (WF32)
          C[(size_t)row * ldc + col] = v;
        if (Cb != nullptr && col >= col_lo)
          Cb[(size_t)row * ldcb + (col - col_lo)] = f2bf(v);
      }
}

// ---------------------------------------------------------------------------
// split-K reduce: out = aux + sum_{s<S} part[s]   (fp32, float4)
// ---------------------------------------------------------------------------
template <int S>
__global__ void __launch_bounds__(256) reduce_add_kernel(
    const float* __restrict__ part, int stride4,
    const float* __restrict__ aux, float* __restrict__ out, int n4)
{
  int idx = blockIdx.x * 256 + threadIdx.x;
  if (idx < n4) {
    float4 v = ((const float4*)aux)[idx];
#pragma unroll
    for (int s = 0; s < S; ++s) {
      float4 p = ((const float4*)part)[(size_t)s * stride4 + idx];
      v.x += p.x; v.y += p.y; v.z += p.z; v.w += p.w;
    }
    ((float4*)out)[idx] = v;
  }
}

// ---------------------------------------------------------------------------
// Fused: h2 = hidden + sum_s part[s]; hn_bf = rmsnorm(h2)*w  (one block/row)
// ---------------------------------------------------------------------------
__global__ void __launch_bounds__(256) reduce_rms_kernel(
    const float* __restrict__ part, int stride,   // stride in floats
    const float* __restrict__ hidden,
    const float* __restrict__ w,
    float* __restrict__ h2, ushort_t* __restrict__ hn)
{
  const int row = blockIdx.x;
  const int c0 = threadIdx.x * 8;            // 2048/256 = 8 floats/thread
  float4 v0 = *(const float4*)(hidden + (size_t)row * DMODEL + c0);
  float4 v1 = *(const float4*)(hidden + (size_t)row * DMODEL + c0 + 4);
#pragma unroll
  for (int s = 0; s < 4; ++s) {
    const float* p = part + (size_t)s * stride + (size_t)row * DMODEL + c0;
    float4 p0 = *(const float4*)p;
    float4 p1 = *(const float4*)(p + 4);
    v0.x += p0.x; v0.y += p0.y; v0.z += p0.z; v0.w += p0.w;
    v1.x += p1.x; v1.y += p1.y; v1.z += p1.z; v1.w += p1.w;
  }
  *(float4*)(h2 + (size_t)row * DMODEL + c0)     = v0;
  *(float4*)(h2 + (size_t)row * DMODEL + c0 + 4) = v1;
  float ss = v0.x*v0.x + v0.y*v0.y + v0.z*v0.z + v0.w*v0.w
           + v1.x*v1.x + v1.y*v1.y + v1.z*v1.z + v1.w*v1.w;
#pragma unroll
  for (int off = 32; off > 0; off >>= 1) ss += __shfl_down(ss, off);
  __shared__ float red[5];
  const int lane = threadIdx.x & 63, wv = threadIdx.x >> 6;
  if (lane == 0) red[wv] = ss;
  __syncthreads();
  if (threadIdx.x == 0)
    red[4] = rsqrtf((red[0] + red[1] + red[2] + red[3]) / (float)DMODEL + 1e-5f);
  __syncthreads();
  const float scale = red[4];
  float4 w0 = *(const float4*)(w + c0);
  float4 w1 = *(const float4*)(w + c0 + 4);
  union { ushort_t u[8]; uint4 q; } o;
  o.u[0] = f2bf(v0.x * scale * w0.x); o.u[1] = f2bf(v0.y * scale * w0.y);
  o.u[2] = f2bf(v0.z * scale * w0.z); o.u[3] = f2bf(v0.w * scale * w0.w);
  o.u[4] = f2bf(v1.x * scale * w1.x); o.u[5] = f2bf(v1.y * scale * w1.y);
  o.u[6] = f2bf(v1.z * scale * w1.z); o.u[7] = f2bf(v1.w * scale * w1.w);
  *(uint4*)(hn + (size_t)row * DMODEL + c0) = o.q;
}

// ---------------------------------------------------------------------------
// RMSNorm (fp32 in, bf16 out)
// ---------------------------------------------------------------------------
__global__ void __launch_bounds__(256) rmsnorm_kernel(
    const float* __restrict__ x, const float* __restrict__ w,
    ushort_t* __restrict__ out)
{
  const int row = blockIdx.x;
  const float* xr = x + (size_t)row * DMODEL;
  float ss = 0.f;
#pragma unroll
  for (int c = threadIdx.x * 4; c < DMODEL; c += 256 * 4) {
    float4 v = *(const float4*)(xr + c);
    ss += v.x * v.x + v.y * v.y + v.z * v.z + v.w * v.w;
  }
#pragma unroll
  for (int off = 32; off > 0; off >>= 1) ss += __shfl_down(ss, off);
  __shared__ float red[5];
  const int lane = threadIdx.x & 63, wv = threadIdx.x >> 6;
  if (lane == 0) red[wv] = ss;
  __syncthreads();
  if (threadIdx.x == 0)
    red[4] = rsqrtf((red[0] + red[1] + red[2] + red[3]) / (float)DMODEL + 1e-5f);
  __syncthreads();
  const float scale = red[4];
  ushort_t* orow = out + (size_t)row * DMODEL;
#pragma unroll
  for (int c = threadIdx.x * 4; c < DMODEL; c += 256 * 4) {
    float4 v  = *(const float4*)(xr + c);
    float4 w4 = *(const float4*)(w + c);
    ushort4 o;
    o.x = f2bf(v.x * scale * w4.x); o.y = f2bf(v.y * scale * w4.y);
    o.z = f2bf(v.z * scale * w4.z); o.w = f2bf(v.w * scale * w4.w);
    *(ushort4*)(orow + c) = o;
  }
}

// ---------------------------------------------------------------------------
// Chunk-parallel selective scan, channel-per-lane (16 states in registers,
// no cross-lane ops). NCHUNK=64 chunks of CLEN=16.
// Thread gt: channel i = gt & 4095, chunk c = gt >> 12.
// ---------------------------------------------------------------------------
__global__ void __launch_bounds__(256) scan_phase1(
    const float* __restrict__ zx, const float* __restrict__ dt,
    const float* __restrict__ A_log,
    float* __restrict__ hend, float* __restrict__ sdtb)
{
  const int gt = blockIdx.x * 256 + threadIdx.x;   // 0..262143
  const int i  = gt & 4095;
  const int c  = gt >> 12;
  const int l0 = c * CLEN;

  float a[16];
  *(float4*)&a[0]  = *(const float4*)(A_log + i * 16 + 0);
  *(float4*)&a[4]  = *(const float4*)(A_log + i * 16 + 4);
  *(float4*)&a[8]  = *(const float4*)(A_log + i * 16 + 8);
  *(float4*)&a[12] = *(const float4*)(A_log + i * 16 + 12);
#pragma unroll
  for (int n = 0; n < 16; ++n) a[n] = -__expf(a[n]);

  float h[16];
#pragma unroll
  for (int n = 0; n < 16; ++n) h[n] = 0.f;
  float sdt = 0.f;

  const int xci = DINNER + ((i >> 6) << 4) + (i & 15);
  const int bci = DINNER + DXB + ((i >> 6) << 4);
  const float* zr = zx + (size_t)l0 * ZROW;
  const float* dr = dt + (size_t)l0 * DINNER + i;

#pragma unroll 4
  for (int l = 0; l < CLEN; ++l) {
    const float* row = zr + l * ZROW;
    const float d = dr[l * DINNER];
    const float x = row[xci];
    float B[16];
    *(float4*)&B[0]  = *(const float4*)(row + bci);
    *(float4*)&B[4]  = *(const float4*)(row + bci + 4);
    *(float4*)&B[8]  = *(const float4*)(row + bci + 8);
    *(float4*)&B[12] = *(const float4*)(row + bci + 12);
    sdt += d;
    const float dtx = d * x;
#pragma unroll
    for (int n = 0; n < 16; ++n)
      h[n] = __expf(d * a[n]) * h[n] + dtx * B[n];
  }

  float* he = hend + ((size_t)c * 65536 + i * 16);
  *(float4*)(he + 0)  = *(float4*)&h[0];
  *(float4*)(he + 4)  = *(float4*)&h[4];
  *(float4*)(he + 8)  = *(float4*)&h[8];
  *(float4*)(he + 12) = *(float4*)&h[12];
  sdtb[c * 4096 + i] = sdt;
}

__global__ void __launch_bounds__(256) scan_phase2(
    const float* __restrict__ hend, const float* __restrict__ sdtb,
    const float* __restrict__ A_log,
    float* __restrict__ hstart)
{
  const int cs = blockIdx.x * 256 + threadIdx.x;   // 0..65535 = i*16+n
  const float a = -__expf(A_log[cs]);
  const int i  = cs >> 4;
  float H = 0.f;
#pragma unroll 8
  for (int c = 0; c < NCHUNK; ++c) {
    hstart[c * 65536 + cs] = H;
    H = __expf(a * sdtb[c * 4096 + i]) * H + hend[c * 65536 + cs];
  }
}

__global__ void __launch_bounds__(256) scan_phase3(
    const float* __restrict__ zx, const float* __restrict__ dt,
    const float* __restrict__ A_log, const float* __restrict__ D_skip,
    const float* __restrict__ hstart,
    ushort_t* __restrict__ y)
{
  const int gt = blockIdx.x * 256 + threadIdx.x;   // 0..262143
  const int i  = gt & 4095;
  const int c  = gt >> 12;
  const int l0 = c * CLEN;

  float a[16];
  *(float4*)&a[0]  = *(const float4*)(A_log + i * 16 + 0);
  *(float4*)&a[4]  = *(const float4*)(A_log + i * 16 + 4);
  *(float4*)&a[8]  = *(const float4*)(A_log + i * 16 + 8);
  *(float4*)&a[12] = *(const float4*)(A_log + i * 16 + 12);
#pragma unroll
  for (int n = 0; n < 16; ++n) a[n] = -__expf(a[n]);
  const float dsk = D_skip[i];

  float h[16];
  const float* hs = hstart + ((size_t)c * 65536 + i * 16);
  *(float4*)&h[0]  = *(const float4*)(hs + 0);
  *(float4*)&h[4]  = *(const float4*)(hs + 4);
  *(float4*)&h[8]  = *(const float4*)(hs + 8);
  *(float4*)&h[12] = *(const float4*)(hs + 12);

  const int xci = DINNER + ((i >> 6) << 4) + (i & 15);
  const int bci = DINNER + DXB + ((i >> 6) << 4);
  const int cci = DINNER + 2 * DXB + (i & ~15);
  const float* zr = zx + (size_t)l0 * ZROW;
  const float* dr = dt + (size_t)l0 * DINNER + i;
  ushort_t*    py = y + (size_t)l0 * DINNER + i;

#pragma unroll 2
  for (int l = 0; l < CLEN; ++l) {
    const float* row = zr + l * ZROW;
    const float d = dr[l * DINNER];
    const float x = row[xci];
    const float z = row[i];
    float B[16], C[16];
    *(float4*)&B[0]  = *(const float4*)(row + bci);
    *(float4*)&B[4]  = *(const float4*)(row + bci + 4);
    *(float4*)&B[8]  = *(const float4*)(row + bci + 8);
    *(float4*)&B[12] = *(const float4*)(row + bci + 12);
    *(float4*)&C[0]  = *(const float4*)(row + cci);
    *(float4*)&C[4]  = *(const float4*)(row + cci + 4);
    *(float4*)&C[8]  = *(const float4*)(row + cci + 8);
    *(float4*)&C[12] = *(const float4*)(row + cci + 12);
    const float dtx = d * x;
    float p0 = 0.f, p1 = 0.f, p2 = 0.f, p3 = 0.f;
#pragma unroll
    for (int n = 0; n < 4; ++n) {
      h[n]      = __expf(d * a[n])      * h[n]      + dtx * B[n];
      h[n + 4]  = __expf(d * a[n + 4])  * h[n + 4]  + dtx * B[n + 4];
      h[n + 8]  = __expf(d * a[n + 8])  * h[n + 8]  + dtx * B[n + 8];
      h[n + 12] = __expf(d * a[n + 12]) * h[n + 12] + dtx * B[n + 12];
      p0 += C[n] * h[n];
      p1 += C[n + 4] * h[n + 4];
      p2 += C[n + 8] * h[n + 8];
      p3 += C[n + 12] * h[n + 12];
    }
    const float p = (p0 + p1) + (p2 + p3);
    const float sz = z / (1.f + __expf(-z));
    py[l * DINNER] = f2bf((p + dsk * x) * sz);
  }
}

// ---------------------------------------------------------------------------
// hm = silu(gate) * up  (bf16 in, bf16 out), 8 elems/thread
// ---------------------------------------------------------------------------
__global__ void __launch_bounds__(256) silu_mul_kernel(
    const ushort_t* __restrict__ g, const ushort_t* __restrict__ u,
    ushort_t* __restrict__ out, int n8)
{
  const int idx = blockIdx.x * 256 + threadIdx.x;
  if (idx < n8) {
    union { uint4 v; ushort_t u[8]; } gv, uv, ov;
    gv.v = ((const uint4*)g)[idx];
    uv.v = ((const uint4*)u)[idx];
#pragma unroll
    for (int j = 0; j < 8; ++j) {
      float gf = bf2f(gv.u[j]), uf = bf2f(uv.u[j]);
      ov.u[j] = f2bf(gf / (1.f + __expf(-gf)) * uf);
    }
    ((uint4*)out)[idx] = ov.v;
  }
}

// ---------------------------------------------------------------------------
extern "C" void kernel_launch(void* const* d_in, const int* in_sizes, int n_in,
                              void* d_out, int out_size, void* d_ws, size_t ws_size,
                              hipStream_t stream)
{
  const float* hidden    = (const float*)d_in[0];
  const float* rms1_w    = (const float*)d_in[1];
  const float* in_proj_w = (const float*)d_in[2];
  const float* dt_proj_w = (const float*)d_in[3];
  const float* dt_proj_b = (const float*)d_in[4];
  const float* A_log     = (const float*)d_in[5];
  const float* D_skip    = (const float*)d_in[6];
  const float* out_proj_w= (const float*)d_in[7];
  const float* rms2_w    = (const float*)d_in[8];
  const float* gate_w    = (const float*)d_in[9];
  const float* up_w      = (const float*)d_in[10];
  const float* down_w    = (const float*)d_in[11];
  float* out = (float*)d_out;

  char* ws = (char*)d_ws;
  // ---- arena (ends 169,607,168; ws proven >= 177,471,488) ----
  ushort_t* h_norm_bf = (ushort_t*)(ws + 0);            // 4 MB
  float*    h2        = (float*)   (ws + 4194304);      // 8 MB
  ushort_t* hn_bf     = (ushort_t*)(ws + 12582912);     // 4 MB
  // SLAB1 [16,777,216 .. 67,108,864): zxbcdt -> part1 -> gate/up/hm
  float*    zxbcdt    = (float*)   (ws + 16777216);     // 42,467,328
  float*    part1     = (float*)   (ws + 16777216);     // 33,554,432 (after scan)
  ushort_t* gate_bf   = (ushort_t*)(ws + 16777216);     // 16 MB (after reduce_rms)
  ushort_t* up_bf     = (ushort_t*)(ws + 33554432);     // 16 MB
  ushort_t* hm_bf     = (ushort_t*)(ws + 50331648);     // 16 MB
  // [67,108,864 .. 118,489,088): dtbuf+hend+hstart+sdt -> part2
  float*    dtbuf     = (float*)   (ws + 67108864);     // 16 MB
  float*    part2     = (float*)   (ws + 67108864);     // 33,554,432 (after scan)
  float*    hend_s    = (float*)   (ws + 83886080);     // 16 MB
  float*    hstart_s  = (float*)   (ws + 100663296);    // 16 MB
  float*    sdtb_s    = (float*)   (ws + 117440512);    //  1 MB
  ushort_t* ybuf_bf   = (ushort_t*)(ws + 118489088);    //  8 MB
  ushort_t* dtA_bf    = (ushort_t*)(ws + 126877696);    //  262,144
  ushort_t* wbuf      = (ushort_t*)(ws + 127139840);    // 42,467,328

  // 1) rmsnorm1 -> bf16
  rmsnorm_kernel<<<L_SEQ, 256, 0, stream>>>(hidden, rms1_w, h_norm_bf);
  // 2) in_proj -> zxbcdt fp32 (+ bf16 dt slice)
  cvt_kernel<<<(ZROW * DMODEL / 8 + 255) / 256, 256, 0, stream>>>(in_proj_w, wbuf, ZROW * DMODEL / 8);
  gemm_bf16<4, 4, 0, true><<<dim3(ZROW / 128, L_SEQ / 128, 1), 256, 0, stream>>>(
      h_norm_bf, DMODEL, wbuf, DMODEL, zxbcdt, ZROW, DMODEL, nullptr,
      dtA_bf, 2 * DINNER + 2 * DXB, DTRANK);
  // 3) dt = softplus(dt_in @ dt_proj_w.T + b)
  cvt_kernel<<<(DINNER * DTRANK / 8 + 255) / 256, 256, 0, stream>>>(dt_proj_w, wbuf, DINNER * DTRANK / 8);
  gemm_bf16<2, 4, 1, true><<<dim3(DINNER / 128, L_SEQ / 64, 1), 256, 0, stream>>>(
      dtA_bf, DTRANK, wbuf, DTRANK, dtbuf, DINNER, DTRANK, dt_proj_b,
      nullptr, 0, 0);
  // 4) chunk-parallel scan -> ybuf bf16
  scan_phase1<<<1024, 256, 0, stream>>>(zxbcdt, dtbuf, A_log, hend_s, sdtb_s);
  scan_phase2<<<256, 256, 0, stream>>>(hend_s, sdtb_s, A_log, hstart_s);
  scan_phase3<<<1024, 256, 0, stream>>>(zxbcdt, dtbuf, A_log, D_skip, hstart_s, ybuf_bf);
  // 5) out_proj split-K x4 -> part1; fused reduce(+hidden)+rmsnorm2 -> h2, hn_bf
  cvt_kernel<<<(DMODEL * DINNER / 8 + 255) / 256, 256, 0, stream>>>(out_proj_w, wbuf, DMODEL * DINNER / 8);
  gemm_bf16<2, 4, 0, true><<<dim3(DMODEL / 128, L_SEQ / 64, 4), 256, 0, stream>>>(
      ybuf_bf, DINNER, wbuf, DINNER, part1, DMODEL, DINNER / 4, nullptr,
      nullptr, 0, 0);
  reduce_rms_kernel<<<L_SEQ, 256, 0, stream>>>(
      part1, L_SEQ * DMODEL, hidden, rms2_w, h2, hn_bf);
  // 6) gate / up (bf16-only outputs)
  cvt_kernel<<<(INTER * DMODEL / 8 + 255) / 256, 256, 0, stream>>>(gate_w, wbuf, INTER * DMODEL / 8);
  gemm_bf16<4, 4, 0, false><<<dim3(INTER / 128, L_SEQ / 128, 1), 256, 0, stream>>>(
      hn_bf, DMODEL, wbuf, DMODEL, nullptr, INTER, DMODEL, nullptr,
      gate_bf, 0, INTER);
  cvt_kernel<<<(INTER * DMODEL / 8 + 255) / 256, 256, 0, stream>>>(up_w, wbuf, INTER * DMODEL / 8);
  gemm_bf16<4, 4, 0, false><<<dim3(INTER / 128, L_SEQ / 128, 1), 256, 0, stream>>>(
      hn_bf, DMODEL, wbuf, DMODEL, nullptr, INTER, DMODEL, nullptr,
      up_bf, 0, INTER);
  // 7) hm = silu(gate) * up -> bf16
  silu_mul_kernel<<<(L_SEQ * INTER / 8) / 256, 256, 0, stream>>>(
      gate_bf, up_bf, hm_bf, L_SEQ * INTER / 8);
  // 8) down split-K x4 -> part2; reduce (+h2) -> out
  cvt_kernel<<<(DMODEL * INTER / 8 + 255) / 256, 256, 0, stream>>>(down_w, wbuf, DMODEL * INTER / 8);
  gemm_bf16<2, 4, 0, true><<<dim3(DMODEL / 128, L_SEQ / 64, 4), 256, 0, stream>>>(
      hm_bf, INTER, wbuf, INTER, part2, DMODEL, INTER / 4, nullptr,
      nullptr, 0, 0);
  reduce_add_kernel<4><<<(L_SEQ * DMODEL / 4) / 256, 256, 0, stream>>>(
      part2, L_SEQ * DMODEL / 4, h2, out, L_SEQ * DMODEL / 4);
}